// Round 2
// baseline (275.654 us; speedup 1.0000x reference)
//
#include <hip/hip_runtime.h>

typedef float f32x4 __attribute__((ext_vector_type(4)));
typedef short bf16x8 __attribute__((ext_vector_type(8)));

#define NTOK 8192
#define DIM  1024
#define NE   8
#define NH   512
#define NO   1024

static __device__ __forceinline__ unsigned short f2bf(float f) {
  unsigned u = __float_as_uint(f);
  u += 0x7fffu + ((u >> 16) & 1u);
  return (unsigned short)(u >> 16);
}
static __device__ __forceinline__ unsigned pk2(float a, float b) {
  return (unsigned)f2bf(a) | ((unsigned)f2bf(b) << 16);
}

static __device__ __forceinline__ f32x4 mfma_bf16(bf16x8 a, bf16x8 b, f32x4 c) {
  return __builtin_amdgcn_mfma_f32_16x16x32_bf16(a, b, c, 0, 0, 0);
}

// ---------------------------------------------------------------------------
// Gate: logits = x @ wg^T in fp64 (match np ranking), top-4 -> mask [N][E]
// one wave per token, 4 tokens per 256-thread block
// ---------------------------------------------------------------------------
__global__ __launch_bounds__(256) void gate_kernel(
    const float* __restrict__ x, const float* __restrict__ wg,
    float* __restrict__ mask)
{
  const int lane = threadIdx.x & 63;
  const int wv = threadIdx.x >> 6;
  const int n = blockIdx.x * 4 + wv;
  const float* xr = x + (size_t)n * DIM;
  float4 v[4];
#pragma unroll
  for (int i = 0; i < 4; ++i) v[i] = *(const float4*)(xr + i * 256 + lane * 4);
  double logit[NE];
#pragma unroll
  for (int e = 0; e < NE; ++e) {
    const float* wr = wg + e * DIM;
    double s = 0.0;
#pragma unroll
    for (int i = 0; i < 4; ++i) {
      float4 g = *(const float4*)(wr + i * 256 + lane * 4);
      s += (double)v[i].x * g.x + (double)v[i].y * g.y +
           (double)v[i].z * g.z + (double)v[i].w * g.w;
    }
#pragma unroll
    for (int off = 32; off; off >>= 1) s += __shfl_down(s, off);
    logit[e] = s;
  }
  if (lane == 0) {
    unsigned sel = 0;
#pragma unroll
    for (int t = 0; t < 4; ++t) {
      int best = 0; double bv = -1.0e300;
#pragma unroll
      for (int e = 0; e < NE; ++e)
        if (!((sel >> e) & 1) && logit[e] > bv) { bv = logit[e]; best = e; }
      sel |= 1u << best;
    }
#pragma unroll
    for (int e = 0; e < NE; ++e)
      mask[(size_t)n * NE + e] = ((sel >> e) & 1) ? 1.0f : 0.0f;
  }
}

// ---------------------------------------------------------------------------
// Weight pack: fp32 -> bf16, fragment-major layout so a wave's B-fragment
// load is one fully-coalesced 1KB global_load_dwordx4.
// w1p chunk t = ((e*32+nt)*32+ks)*64+lane ; element j = w1[e][nt*16+(l&15)][ks*32+(l>>4)*8+j]
// ---------------------------------------------------------------------------
__global__ __launch_bounds__(256) void pack_w1_kernel(
    const float* __restrict__ w1, unsigned short* __restrict__ w1p)
{
  int t = blockIdx.x * 256 + threadIdx.x;          // 0 .. 524287
  int lane = t & 63, ks = (t >> 6) & 31, nt = (t >> 11) & 31, e = t >> 16;
  int r = nt * 16 + (lane & 15);
  int c = ks * 32 + (lane >> 4) * 8;
  const float* src = w1 + ((size_t)(e * 512 + r)) * 1024 + c;
  float4 f0 = *(const float4*)src;
  float4 f1 = *(const float4*)(src + 4);
  uint4 v;
  v.x = pk2(f0.x, f0.y); v.y = pk2(f0.z, f0.w);
  v.z = pk2(f1.x, f1.y); v.w = pk2(f1.z, f1.w);
  *(uint4*)(w1p + (size_t)t * 8) = v;
}

__global__ __launch_bounds__(256) void pack_w2_kernel(
    const float* __restrict__ w2, unsigned short* __restrict__ w2p)
{
  int t = blockIdx.x * 256 + threadIdx.x;          // 0 .. 524287
  int lane = t & 63, ks = (t >> 6) & 15, ot = (t >> 10) & 63, e = t >> 16;
  int o = ot * 16 + (lane & 15);
  int h = ks * 32 + (lane >> 4) * 8;
  const float* src = w2 + ((size_t)(e * 1024 + o)) * 512 + h;
  float4 f0 = *(const float4*)src;
  float4 f1 = *(const float4*)(src + 4);
  uint4 v;
  v.x = pk2(f0.x, f0.y); v.y = pk2(f0.z, f0.w);
  v.z = pk2(f1.x, f1.y); v.w = pk2(f1.z, f1.w);
  *(uint4*)(w2p + (size_t)t * 8) = v;
}

// ---------------------------------------------------------------------------
// Fused MoE FFN: 256 blocks x 8 waves, BM=32 tokens/block.
// Per expert: GEMM1 (X[32x1024] @ W1[e]^T -> h[32x512], waves split H),
// relu*mask -> hs (bf16, swizzled LDS), GEMM2 (hs @ W2[e]^T, waves split O,
// accumulate 32x128 slice in registers across all 8 experts).
// ---------------------------------------------------------------------------
__global__ __launch_bounds__(512, 2) void moe_ffn(
    const float* __restrict__ x, const unsigned short* __restrict__ w1p,
    const unsigned short* __restrict__ w2p, const float* __restrict__ mask,
    float* __restrict__ out)
{
  __shared__ unsigned short xs[32 * 1024];   // 64 KB, swizzled bf16 X tile
  __shared__ unsigned short hs[32 * 512];    // 32 KB, swizzled bf16 h tile
  __shared__ float mk[32 * NE];              // 1 KB mask tile

  const int tid = threadIdx.x;
  const int lane = tid & 63;
  const int wv = tid >> 6;
  const int row0 = blockIdx.x * 32;
  const int arow = lane & 15;
  const int kch = lane >> 4;

  // stage X: 32 rows x 1024 f32 -> bf16, XOR-swizzled (G4: row-major tile
  // at 2KB stride is a 16-way bank conflict on ds_read_b128 without it)
  for (int c = tid; c < 4096; c += 512) {
    int r = c >> 7;
    int off = (c & 127) * 8;
    const float* src = x + (size_t)(row0 + r) * DIM + off;
    float4 f0 = *(const float4*)src;
    float4 f1 = *(const float4*)(src + 4);
    uint4 v;
    v.x = pk2(f0.x, f0.y); v.y = pk2(f0.z, f0.w);
    v.z = pk2(f1.x, f1.y); v.w = pk2(f1.z, f1.w);
    int byte = (r * 2048 + off * 2) ^ ((r & 7) << 4);
    *(uint4*)((char*)xs + byte) = v;
  }
  if (tid < 32 * NE) mk[tid] = mask[(size_t)row0 * NE + tid];
  __syncthreads();

  f32x4 oacc[2][8];
#pragma unroll
  for (int m = 0; m < 2; ++m)
#pragma unroll
    for (int n = 0; n < 8; ++n) oacc[m][n] = f32x4{0.f, 0.f, 0.f, 0.f};

  for (int e = 0; e < NE; ++e) {
    // ---- GEMM1: h[32 x 64-slice] = X @ W1[e]^T -------------------------
    f32x4 hacc[2][4];
#pragma unroll
    for (int m = 0; m < 2; ++m)
#pragma unroll
      for (int n = 0; n < 4; ++n) hacc[m][n] = f32x4{0.f, 0.f, 0.f, 0.f};

    const unsigned short* b1 = w1p + ((size_t)(e * 32 + wv * 4) * 32) * 64 * 8;
    for (int ks = 0; ks < 32; ++ks) {
      int col = ks * 64 + kch * 16;
      bf16x8 a0 = *(const bf16x8*)((const char*)xs + ((arow * 2048 + col) ^ ((arow & 7) << 4)));
      bf16x8 a1 = *(const bf16x8*)((const char*)xs + (((arow + 16) * 2048 + col) ^ ((arow & 7) << 4)));
#pragma unroll
      for (int n = 0; n < 4; ++n) {
        bf16x8 b = *(const bf16x8*)(b1 + ((size_t)(n * 32 + ks) * 64 + lane) * 8);
        hacc[0][n] = mfma_bf16(a0, b, hacc[0][n]);
        hacc[1][n] = mfma_bf16(a1, b, hacc[1][n]);
      }
    }
    __syncthreads();   // previous expert's GEMM2 done reading hs

    // ---- epilogue1: relu * mask -> hs (bf16, swizzled) -----------------
#pragma unroll
    for (int m = 0; m < 2; ++m)
#pragma unroll
      for (int n = 0; n < 4; ++n)
#pragma unroll
        for (int j = 0; j < 4; ++j) {
          int row = m * 16 + kch * 4 + j;
          int colh = wv * 64 + n * 16 + arow;
          float v = fmaxf(hacc[m][n][j], 0.0f) * mk[row * NE + e];
          int byte = (row * 1024 + colh * 2) ^ ((row & 7) << 4);
          *(unsigned short*)((char*)hs + byte) = f2bf(v);
        }
    __syncthreads();   // hs ready for all waves

    // ---- GEMM2: out[32 x 128-slice] += hs @ W2[e]^T --------------------
    const unsigned short* b2 = w2p + ((size_t)(e * 64 + wv * 8) * 16) * 64 * 8;
    for (int ks = 0; ks < 16; ++ks) {
      int col = ks * 64 + kch * 16;
      bf16x8 a0 = *(const bf16x8*)((const char*)hs + ((arow * 1024 + col) ^ ((arow & 7) << 4)));
      bf16x8 a1 = *(const bf16x8*)((const char*)hs + (((arow + 16) * 1024 + col) ^ ((arow & 7) << 4)));
#pragma unroll
      for (int n = 0; n < 8; ++n) {
        bf16x8 b = *(const bf16x8*)(b2 + ((size_t)(n * 16 + ks) * 64 + lane) * 8);
        oacc[0][n] = mfma_bf16(a0, b, oacc[0][n]);
        oacc[1][n] = mfma_bf16(a1, b, oacc[1][n]);
      }
    }
  }

  // ---- write out (each element exactly once) ---------------------------
#pragma unroll
  for (int m = 0; m < 2; ++m)
#pragma unroll
    for (int n = 0; n < 8; ++n)
#pragma unroll
      for (int j = 0; j < 4; ++j) {
        int row = row0 + m * 16 + kch * 4 + j;
        int col = wv * 128 + n * 16 + arow;
        out[(size_t)row * NO + col] = oacc[m][n][j];
      }
}

extern "C" void kernel_launch(void* const* d_in, const int* in_sizes, int n_in,
                              void* d_out, int out_size, void* d_ws, size_t ws_size,
                              hipStream_t stream) {
  (void)in_sizes; (void)n_in; (void)out_size; (void)ws_size;
  const float* x  = (const float*)d_in[0];
  const float* wg = (const float*)d_in[1];
  const float* w1 = (const float*)d_in[2];
  const float* w2 = (const float*)d_in[3];
  float* out = (float*)d_out;
  char* ws = (char*)d_ws;
  unsigned short* w1p = (unsigned short*)ws;                        // 8 MB
  unsigned short* w2p = (unsigned short*)(ws + ((size_t)8 << 20));  // 8 MB
  float* mask = (float*)(ws + ((size_t)16 << 20));                  // 256 KB

  gate_kernel<<<2048, 256, 0, stream>>>(x, wg, mask);
  pack_w1_kernel<<<2048, 256, 0, stream>>>(w1, w1p);
  pack_w2_kernel<<<2048, 256, 0, stream>>>(w2, w2p);
  moe_ffn<<<256, 512, 0, stream>>>(x, w1p, w2p, mask, out);
}

// Round 3
// 200.532 us; speedup vs baseline: 1.3746x; 1.3746x over previous
//
#include <hip/hip_runtime.h>

typedef float f32x4 __attribute__((ext_vector_type(4)));
typedef short bf16x8 __attribute__((ext_vector_type(8)));

#define NTOK 8192
#define DIM  1024
#define NE   8
#define NH   512
#define NO   1024

static __device__ __forceinline__ unsigned short f2bf(float f) {
  unsigned u = __float_as_uint(f);
  u += 0x7fffu + ((u >> 16) & 1u);
  return (unsigned short)(u >> 16);
}
static __device__ __forceinline__ unsigned pk2(float a, float b) {
  return (unsigned)f2bf(a) | ((unsigned)f2bf(b) << 16);
}

static __device__ __forceinline__ f32x4 mfma_bf16(bf16x8 a, bf16x8 b, f32x4 c) {
  return __builtin_amdgcn_mfma_f32_16x16x32_bf16(a, b, c, 0, 0, 0);
}

// ---------------------------------------------------------------------------
// Gate: logits = x @ wg^T in fp64 (match np ranking), top-4 -> mask [N][E]
// (unchanged from round 2 — ranking passed; keep bit-identical)
// ---------------------------------------------------------------------------
__global__ __launch_bounds__(256) void gate_kernel(
    const float* __restrict__ x, const float* __restrict__ wg,
    float* __restrict__ mask)
{
  const int lane = threadIdx.x & 63;
  const int wv = threadIdx.x >> 6;
  const int n = blockIdx.x * 4 + wv;
  const float* xr = x + (size_t)n * DIM;
  float4 v[4];
#pragma unroll
  for (int i = 0; i < 4; ++i) v[i] = *(const float4*)(xr + i * 256 + lane * 4);
  double logit[NE];
#pragma unroll
  for (int e = 0; e < NE; ++e) {
    const float* wr = wg + e * DIM;
    double s = 0.0;
#pragma unroll
    for (int i = 0; i < 4; ++i) {
      float4 g = *(const float4*)(wr + i * 256 + lane * 4);
      s += (double)v[i].x * g.x + (double)v[i].y * g.y +
           (double)v[i].z * g.z + (double)v[i].w * g.w;
    }
#pragma unroll
    for (int off = 32; off; off >>= 1) s += __shfl_down(s, off);
    logit[e] = s;
  }
  if (lane == 0) {
    unsigned sel = 0;
#pragma unroll
    for (int t = 0; t < 4; ++t) {
      int best = 0; double bv = -1.0e300;
#pragma unroll
      for (int e = 0; e < NE; ++e)
        if (!((sel >> e) & 1) && logit[e] > bv) { bv = logit[e]; best = e; }
      sel |= 1u << best;
    }
#pragma unroll
    for (int e = 0; e < NE; ++e)
      mask[(size_t)n * NE + e] = ((sel >> e) & 1) ? 1.0f : 0.0f;
  }
}

// ---------------------------------------------------------------------------
// Weight packs (unchanged): fragment-major bf16.
// w1p [e][nt:32][ks:32][lane:64][j:8]; elem = w1[e][nt*16+(l&15)][ks*32+(l>>4)*8+j]
// ---------------------------------------------------------------------------
__global__ __launch_bounds__(256) void pack_w1_kernel(
    const float* __restrict__ w1, unsigned short* __restrict__ w1p)
{
  int t = blockIdx.x * 256 + threadIdx.x;
  int lane = t & 63, ks = (t >> 6) & 31, nt = (t >> 11) & 31, e = t >> 16;
  int r = nt * 16 + (lane & 15);
  int c = ks * 32 + (lane >> 4) * 8;
  const float* src = w1 + ((size_t)(e * 512 + r)) * 1024 + c;
  float4 f0 = *(const float4*)src;
  float4 f1 = *(const float4*)(src + 4);
  uint4 v;
  v.x = pk2(f0.x, f0.y); v.y = pk2(f0.z, f0.w);
  v.z = pk2(f1.x, f1.y); v.w = pk2(f1.z, f1.w);
  *(uint4*)(w1p + (size_t)t * 8) = v;
}

__global__ __launch_bounds__(256) void pack_w2_kernel(
    const float* __restrict__ w2, unsigned short* __restrict__ w2p)
{
  int t = blockIdx.x * 256 + threadIdx.x;
  int lane = t & 63, ks = (t >> 6) & 15, ot = (t >> 10) & 63, e = t >> 16;
  int o = ot * 16 + (lane & 15);
  int h = ks * 32 + (lane >> 4) * 8;
  const float* src = w2 + ((size_t)(e * 1024 + o)) * 512 + h;
  float4 f0 = *(const float4*)src;
  float4 f1 = *(const float4*)(src + 4);
  uint4 v;
  v.x = pk2(f0.x, f0.y); v.y = pk2(f0.z, f0.w);
  v.z = pk2(f1.x, f1.y); v.w = pk2(f1.z, f1.w);
  *(uint4*)(w2p + (size_t)t * 8) = v;
}

// ---------------------------------------------------------------------------
// Fused MoE FFN, round 3: 256 blocks x 16 waves, BM=32.
// LDS tiles stored FRAGMENT-MAJOR (same layout as packed weights) so every
// A-fragment load is one contiguous conflict-free 1KB ds_read_b128.
//   xs frag f = ks*2+m   (ks 0..31, m 0..1): X[m*16+(l&15)][ks*32+(l>>4)*8+j]
//   hs frag f = ks2*2+m  (ks2 0..15):        h[m*16+(l&15)][ks2*32+(l>>4)*8+j]
// GEMM1: wave wv owns h cols [wv*32, wv*32+32)  (2m x 2n)
// GEMM2: wave wv owns out cols [wv*64, wv*64+64) (2m x 4n), acc over experts
// ---------------------------------------------------------------------------
__global__ __launch_bounds__(1024, 4) void moe_ffn(
    const float* __restrict__ x, const unsigned short* __restrict__ w1p,
    const unsigned short* __restrict__ w2p, const float* __restrict__ mask,
    float* __restrict__ out)
{
  __shared__ unsigned short xs[64 * 64 * 8];   // 64 KB: 64 frags x 64 lanes x 8
  __shared__ unsigned short hs[32 * 64 * 8];   // 32 KB: 32 frags
  __shared__ float mk[32 * NE];                // 1 KB

  const int tid = threadIdx.x;
  const int lane = tid & 63;
  const int wv = tid >> 6;
  const int row0 = blockIdx.x * 32;
  const int arow = lane & 15;
  const int kch = lane >> 4;

  // ---- stage X into fragment-major LDS (coalesced global reads) ----------
#pragma unroll
  for (int i = 0; i < 4; ++i) {
    int c = i * 1024 + tid;          // 0..4095 = 32 rows x 128 chunks-of-8
    int r = c >> 7;
    int ch = c & 127;
    const float* src = x + (size_t)(row0 + r) * DIM + ch * 8;
    float4 f0 = *(const float4*)src;
    float4 f1 = *(const float4*)(src + 4);
    uint4 v;
    v.x = pk2(f0.x, f0.y); v.y = pk2(f0.z, f0.w);
    v.z = pk2(f1.x, f1.y); v.w = pk2(f1.z, f1.w);
    int f = (ch >> 2) * 2 + (r >> 4);            // ks*2 + m
    int l = ((ch & 3) << 4) | (r & 15);          // kch<<4 | row
    *(uint4*)(xs + ((size_t)(f * 64 + l)) * 8) = v;
  }
  if (tid < 32 * NE) mk[tid] = mask[(size_t)row0 * NE + tid];
  __syncthreads();

  f32x4 oacc[2][4];
#pragma unroll
  for (int m = 0; m < 2; ++m)
#pragma unroll
    for (int n = 0; n < 4; ++n) oacc[m][n] = f32x4{0.f, 0.f, 0.f, 0.f};

  for (int e = 0; e < NE; ++e) {
    // ---- GEMM1: hacc[2m][2n] over K=1024 -------------------------------
    f32x4 hacc[2][2];
#pragma unroll
    for (int m = 0; m < 2; ++m)
#pragma unroll
      for (int n = 0; n < 2; ++n) hacc[m][n] = f32x4{0.f, 0.f, 0.f, 0.f};

    const unsigned short* b1 = w1p + ((size_t)(e * 32 + wv * 2) * 32) * 64 * 8;
#pragma unroll 4
    for (int ks = 0; ks < 32; ++ks) {
      bf16x8 a0 = *(const bf16x8*)(xs + ((size_t)((ks * 2 + 0) * 64 + lane)) * 8);
      bf16x8 a1 = *(const bf16x8*)(xs + ((size_t)((ks * 2 + 1) * 64 + lane)) * 8);
      bf16x8 b0 = *(const bf16x8*)(b1 + ((size_t)(0 * 32 + ks) * 64 + lane) * 8);
      bf16x8 b2 = *(const bf16x8*)(b1 + ((size_t)(1 * 32 + ks) * 64 + lane) * 8);
      hacc[0][0] = mfma_bf16(a0, b0, hacc[0][0]);
      hacc[1][0] = mfma_bf16(a1, b0, hacc[1][0]);
      hacc[0][1] = mfma_bf16(a0, b2, hacc[0][1]);
      hacc[1][1] = mfma_bf16(a1, b2, hacc[1][1]);
    }
    __syncthreads();   // all waves done reading hs (previous expert GEMM2)

    // ---- epilogue1: relu * mask -> hs fragments -------------------------
    // value (hrow = m*16+kch*4+j, hcol = wv*32+n*16+arow) ->
    //   frag f = wv*2+m? NO: f = (hcol>>5)*2 + m = wv*2 + m
    //   lane2 = ((n*2 + (arow>>3)) << 4) | (kch*4 + j);  byte j2 = arow&7
#pragma unroll
    for (int m = 0; m < 2; ++m)
#pragma unroll
      for (int n = 0; n < 2; ++n)
#pragma unroll
        for (int j = 0; j < 4; ++j) {
          float v = fmaxf(hacc[m][n][j], 0.0f) * mk[(m * 16 + kch * 4 + j) * NE + e];
          int l2 = ((n * 2 + (arow >> 3)) << 4) | (kch * 4 + j);
          hs[((size_t)((wv * 2 + m) * 64 + l2)) * 8 + (arow & 7)] = f2bf(v);
        }
    __syncthreads();   // hs ready

    // ---- GEMM2: oacc[2m][4n] += hs @ W2[e]^T ----------------------------
    const unsigned short* b2p = w2p + ((size_t)(e * 64 + wv * 4) * 16) * 64 * 8;
#pragma unroll 4
    for (int ks = 0; ks < 16; ++ks) {
      bf16x8 a0 = *(const bf16x8*)(hs + ((size_t)((ks * 2 + 0) * 64 + lane)) * 8);
      bf16x8 a1 = *(const bf16x8*)(hs + ((size_t)((ks * 2 + 1) * 64 + lane)) * 8);
#pragma unroll
      for (int n = 0; n < 4; ++n) {
        bf16x8 b = *(const bf16x8*)(b2p + ((size_t)(n * 16 + ks) * 64 + lane) * 8);
        oacc[0][n] = mfma_bf16(a0, b, oacc[0][n]);
        oacc[1][n] = mfma_bf16(a1, b, oacc[1][n]);
      }
    }
  }

  // ---- write out --------------------------------------------------------
#pragma unroll
  for (int m = 0; m < 2; ++m)
#pragma unroll
    for (int n = 0; n < 4; ++n)
#pragma unroll
      for (int j = 0; j < 4; ++j) {
        int row = row0 + m * 16 + kch * 4 + j;
        int col = wv * 64 + n * 16 + arow;
        out[(size_t)row * NO + col] = oacc[m][n][j];
      }
}

extern "C" void kernel_launch(void* const* d_in, const int* in_sizes, int n_in,
                              void* d_out, int out_size, void* d_ws, size_t ws_size,
                              hipStream_t stream) {
  (void)in_sizes; (void)n_in; (void)out_size; (void)ws_size;
  const float* x  = (const float*)d_in[0];
  const float* wg = (const float*)d_in[1];
  const float* w1 = (const float*)d_in[2];
  const float* w2 = (const float*)d_in[3];
  float* out = (float*)d_out;
  char* ws = (char*)d_ws;
  unsigned short* w1p = (unsigned short*)ws;                        // 8 MB
  unsigned short* w2p = (unsigned short*)(ws + ((size_t)8 << 20));  // 8 MB
  float* mask = (float*)(ws + ((size_t)16 << 20));                  // 256 KB

  gate_kernel<<<2048, 256, 0, stream>>>(x, wg, mask);
  pack_w1_kernel<<<2048, 256, 0, stream>>>(w1, w1p);
  pack_w2_kernel<<<2048, 256, 0, stream>>>(w2, w2p);
  moe_ffn<<<256, 1024, 0, stream>>>(x, w1p, w2p, mask, out);
}